// Round 5
// baseline (448.150 us; speedup 1.0000x reference)
//
#include <hip/hip_runtime.h>
#include <hip/hip_bf16.h>

#define EMB 64
#define XCOLS 20
#define NSYMP 15
#define BSH 7
#define BSZ 128          // nodes per bucket (1<<BSH)
#define MAXNB 1024       // supports N <= 131072
#define PCHUNK 16384

__global__ void zero_kernel(int* __restrict__ p, int n) {
    int i = blockIdx.x * blockDim.x + threadIdx.x;
    if (i < n) p[i] = 0;
}

// ---------------- fused embed + dual GEMM (layer 1) ----------------
// h = embed(x); outL = h@Wl+bl; outR = h@Wr+br   (h never hits HBM)
__global__ void embed_gemm_kernel(const int* __restrict__ x,
                                  const float* __restrict__ bt,
                                  const float* __restrict__ gt,
                                  const float* __restrict__ st,
                                  const float* __restrict__ Wl, const float* __restrict__ bl,
                                  const float* __restrict__ Wr, const float* __restrict__ br,
                                  float* __restrict__ outL, float* __restrict__ outR, int N) {
    __shared__ float wl[EMB * EMB];
    __shared__ float wr[EMB * EMB];
    __shared__ float hr[256];
    __shared__ int xs[4 * XCOLS];
    for (int i = threadIdx.x; i < EMB * EMB; i += 256) {
        wl[i] = Wl[i];
        wr[i] = Wr[i];
    }
    int ngroups = (N + 3) / 4;
    int r = threadIdx.x >> 6;
    int d = threadIdx.x & 63;
    float blv = bl[d], brv = br[d];
    for (int g = blockIdx.x; g < ngroups; g += gridDim.x) {
        __syncthreads();                    // xs/hr from previous iteration in use
        if (threadIdx.x < 4 * XCOLS) {
            int n2 = g * 4 + threadIdx.x / XCOLS;
            xs[threadIdx.x] = (n2 < N) ? x[(size_t)g * 4 * XCOLS + threadIdx.x] : 0;
        }
        __syncthreads();
        int node = g * 4 + r;
        const int* xrow = &xs[r * XCOLS];
        float val = 0.f;
        if (node < N) {
            int bi = xrow[1] + 2 * xrow[2] + 3 * xrow[3];
            int gg = xrow[4];
            float f = 0.f;
#pragma unroll
            for (int j = 0; j < NSYMP; ++j)
                f += st[(j * 3 + xrow[5 + j]) * EMB + d];
            val = (bt[bi * EMB + d] + gt[gg * EMB + d] + f * (1.f / 15.f)) * (1.f / 3.f);
        }
        hr[threadIdx.x] = val;
        __syncthreads();
        if (node < N) {
            float al = blv, ar = brv;
#pragma unroll
            for (int k = 0; k < EMB; ++k) {
                float hv = hr[r * EMB + k];
                al += hv * wl[k * EMB + d];
                ar += hv * wr[k * EMB + d];
            }
            outL[node * EMB + d] = al;
            outR[node * EMB + d] = ar;
        }
    }
}

// ---------------- dual GEMM (layer 2) ----------------
__global__ void gemm_dual_kernel(const float* __restrict__ h,
                                 const float* __restrict__ Wl, const float* __restrict__ bl,
                                 const float* __restrict__ Wr, const float* __restrict__ br,
                                 float* __restrict__ outL, float* __restrict__ outR, int N) {
    __shared__ float wl[EMB * EMB];
    __shared__ float wr[EMB * EMB];
    __shared__ float hr[2][256];
    for (int i = threadIdx.x; i < EMB * EMB; i += 256) {
        wl[i] = Wl[i];
        wr[i] = Wr[i];
    }
    int ngroups = (N + 3) / 4;
    int r = threadIdx.x >> 6;
    int d = threadIdx.x & 63;
    size_t total = (size_t)N * EMB;
    {
        size_t idx = (size_t)blockIdx.x * 256 + threadIdx.x;
        if (blockIdx.x < ngroups) hr[0][threadIdx.x] = (idx < total) ? h[idx] : 0.f;
    }
    int buf = 0;
    for (int g = blockIdx.x; g < ngroups; g += gridDim.x) {
        __syncthreads();
        int gn = g + gridDim.x;
        if (gn < ngroups) {
            size_t idx = (size_t)gn * 256 + threadIdx.x;
            hr[buf ^ 1][threadIdx.x] = (idx < total) ? h[idx] : 0.f;
        }
        int node = g * 4 + r;
        if (node < N) {
            float al = bl[d], ar = br[d];
#pragma unroll
            for (int k = 0; k < EMB; ++k) {
                float hv = hr[buf][r * EMB + k];
                al += hv * wl[k * EMB + d];
                ar += hv * wr[k * EMB + d];
            }
            outL[node * EMB + d] = al;
            outR[node * EMB + d] = ar;
        }
        buf ^= 1;
    }
}

// ---------------- CSR build via 2-level radix partition ----------------
__global__ void bincount_kernel(const int* __restrict__ ei, int* __restrict__ bcount,
                                int* __restrict__ offs, int E, int NB, int N) {
    __shared__ int lh[MAXNB];
    for (int j = threadIdx.x; j < NB; j += 256) lh[j] = 0;
    __syncthreads();
    for (int i = blockIdx.x * 256 + threadIdx.x; i < E; i += gridDim.x * 256)
        atomicAdd(&lh[ei[E + i] >> BSH], 1);
    __syncthreads();
    for (int j = threadIdx.x; j < NB; j += 256)
        if (lh[j]) atomicAdd(&bcount[j], lh[j]);
    if (blockIdx.x == 0 && threadIdx.x == 0) offs[N] = E;
}

__global__ void bscan_kernel(const int* __restrict__ bcount, int* __restrict__ boffs,
                             int* __restrict__ bcursor, int NB) {
    __shared__ int s[1024];
    int t = threadIdx.x;
    int v0 = (t < NB) ? bcount[t] : 0;
    s[t] = v0;
    __syncthreads();
    for (int off = 1; off < 1024; off <<= 1) {
        int v = (t >= off) ? s[t - off] : 0;
        __syncthreads();
        s[t] += v;
        __syncthreads();
    }
    if (t < NB) {
        boffs[t + 1] = s[t];
        bcursor[t] = s[t] - v0;
    }
    if (t == 0) boffs[0] = 0;
}

__global__ void partition_kernel(const int* __restrict__ ei, int* __restrict__ bcursor,
                                 int* __restrict__ epart, int E, int NB) {
    __shared__ int lh[MAXNB];
    for (int j = threadIdx.x; j < NB; j += 256) lh[j] = 0;
    __syncthreads();
    int base = blockIdx.x * PCHUNK;
    int end = min(E, base + PCHUNK);
    for (int i = base + threadIdx.x; i < end; i += 256)
        atomicAdd(&lh[ei[E + i] >> BSH], 1);
    __syncthreads();
    for (int j = threadIdx.x; j < NB; j += 256) {
        int c = lh[j];
        lh[j] = c ? atomicAdd(&bcursor[j], c) : 0;
    }
    __syncthreads();
    for (int i = base + threadIdx.x; i < end; i += 256) {
        int dst = ei[E + i];
        int src = ei[i];
        int slot = atomicAdd(&lh[dst >> BSH], 1);
        epart[slot] = (src << BSH) | (dst & (BSZ - 1));
    }
}

__global__ void finalize_kernel(const int* __restrict__ epart, const int* __restrict__ boffs,
                                int* __restrict__ offs, int* __restrict__ ssrc, int N) {
    __shared__ int deg[BSZ], pos[BSZ], cur[BSZ];
    int b = blockIdx.x;
    int t = threadIdx.x;
    int n0 = b << BSH;
    int r0 = boffs[b], r1 = boffs[b + 1];
    if (t < BSZ) deg[t] = 0;
    __syncthreads();
    for (int e = r0 + t; e < r1; e += 256)
        atomicAdd(&deg[epart[e] & (BSZ - 1)], 1);
    __syncthreads();
    if (t < BSZ) pos[t] = deg[t];
    __syncthreads();
    for (int off = 1; off < BSZ; off <<= 1) {
        int v = (t < BSZ && t >= off) ? pos[t - off] : 0;
        __syncthreads();
        if (t < BSZ) pos[t] += v;
        __syncthreads();
    }
    if (t < BSZ) {
        int ex = r0 + pos[t] - deg[t];
        cur[t] = ex;
        int node = n0 + t;
        if (node < N) offs[node] = ex;
    }
    __syncthreads();
    for (int e = r0 + t; e < r1; e += 256) {
        int v = epart[e];
        int s = atomicAdd(&cur[v & (BSZ - 1)], 1);
        ssrc[s] = v >> BSH;
    }
}

// ---------------- DPP cross-lane sum helpers (VALU pipe, not LDS) ----------
template <int CTRL>
__device__ __forceinline__ float dpp_add(float v) {
    union { float f; int i; } u, r;
    u.f = v;
    r.i = __builtin_amdgcn_update_dpp(0, u.i, CTRL, 0xF, 0xF, true);
    return v + r.f;
}

template <int L>
__device__ __forceinline__ float reduce_head(float v) {
    v = dpp_add<0xB1>(v);    // quad_perm xor1
    v = dpp_add<0x4E>(v);    // quad_perm xor2
    v = dpp_add<0x141>(v);   // row_half_mirror
    v = dpp_add<0x140>(v);   // row_mirror -> 16-lane sum
    if (L == 2) {
        v += __shfl_xor(v, 16);
        v += __shfl_xor(v, 32);
    }
    return v;
}

// ---------------- GATv2 layer, one wave per destination node ----------------
// Logits are O(1) here (0.1-scale weights), so plain sum-exp == softmax
// without max subtraction; log2(e) folded into att so each edge costs one
// raw v_exp_f32. L=1: out=elu(...); L=2: out = dot(...,linW)+linb.
template <int L>
__global__ void gat_kernel(const float* __restrict__ xl, const float* __restrict__ xr,
                           const int* __restrict__ offs, const int* __restrict__ ssrc,
                           const float* __restrict__ att, const float* __restrict__ bias,
                           const float* __restrict__ linW, const float* __restrict__ linb,
                           float* __restrict__ out, int N) {
    int wid = blockIdx.x * 4 + (threadIdx.x >> 6);
    int lane = threadIdx.x & 63;
    if (wid >= N) return;

    float att_l = att[lane] * 1.4426950408889634f;   // fold log2(e)
    float xr_l = xr[wid * EMB + lane];
    float bias_l = bias[lane];
    int e0 = offs[wid];
    int e1 = offs[wid + 1];

    // self-loop
    float x0 = xl[wid * EMB + lane];
    float t0 = x0 + xr_l;
    t0 = fmaxf(t0, 0.2f * t0);                       // leaky_relu(0.2)
    float p0s = exp2f(reduce_head<L>(att_l * t0));
    float s = p0s;
    float acc = p0s * x0;

    int e = e0;
    for (; e + 4 <= e1; e += 4) {
        int i0 = ssrc[e], i1 = ssrc[e + 1], i2 = ssrc[e + 2], i3 = ssrc[e + 3];
        float a0 = xl[i0 * EMB + lane];
        float a1 = xl[i1 * EMB + lane];
        float a2 = xl[i2 * EMB + lane];
        float a3 = xl[i3 * EMB + lane];
        float u0 = a0 + xr_l; u0 = fmaxf(u0, 0.2f * u0);
        float u1 = a1 + xr_l; u1 = fmaxf(u1, 0.2f * u1);
        float u2 = a2 + xr_l; u2 = fmaxf(u2, 0.2f * u2);
        float u3 = a3 + xr_l; u3 = fmaxf(u3, 0.2f * u3);
        float p0 = exp2f(reduce_head<L>(att_l * u0));
        float p1 = exp2f(reduce_head<L>(att_l * u1));
        float p2 = exp2f(reduce_head<L>(att_l * u2));
        float p3 = exp2f(reduce_head<L>(att_l * u3));
        s += (p0 + p1) + (p2 + p3);
        acc += (p0 * a0 + p1 * a1) + (p2 * a2 + p3 * a3);
    }
    for (; e < e1; ++e) {
        int i0 = ssrc[e];
        float a0 = xl[i0 * EMB + lane];
        float u0 = a0 + xr_l;
        u0 = fmaxf(u0, 0.2f * u0);
        float p0 = exp2f(reduce_head<L>(att_l * u0));
        s += p0;
        acc += p0 * a0;
    }

    float val = acc / (s + 1e-16f) + bias_l;
    if (L == 1) {
        out[wid * EMB + lane] = (val > 0.f) ? val : (__expf(val) - 1.f);
    } else {
        float r = val * linW[lane];
        r = reduce_head<2>(r);
        if (lane == 0) out[wid] = r + linb[0];
    }
}

extern "C" void kernel_launch(void* const* d_in, const int* in_sizes, int n_in,
                              void* d_out, int out_size, void* d_ws, size_t ws_size,
                              hipStream_t stream) {
    const int* x = (const int*)d_in[0];
    const int* ei = (const int*)d_in[1];          // int32 marshalled
    const float* birth_tab = (const float*)d_in[2];
    const float* gender_tab = (const float*)d_in[3];
    const float* symp_tab = (const float*)d_in[4];
    const float* Wl1 = (const float*)d_in[5];
    const float* bl1 = (const float*)d_in[6];
    const float* Wr1 = (const float*)d_in[7];
    const float* br1 = (const float*)d_in[8];
    const float* att1 = (const float*)d_in[9];
    const float* bias1 = (const float*)d_in[10];
    const float* Wl2 = (const float*)d_in[11];
    const float* bl2 = (const float*)d_in[12];
    const float* Wr2 = (const float*)d_in[13];
    const float* br2 = (const float*)d_in[14];
    const float* att2 = (const float*)d_in[15];
    const float* bias2 = (const float*)d_in[16];
    const float* linW = (const float*)d_in[17];
    const float* linb = (const float*)d_in[18];
    float* outp = (float*)d_out;

    int N = in_sizes[0] / XCOLS;   // 100000
    int E = in_sizes[1] / 2;       // 1600000
    int NB = (N + BSZ - 1) >> BSH; // 782

    char* p = (char*)d_ws;
    auto alloc = [&](size_t bytes) {
        void* r = (void*)p;
        p += (bytes + 255) & ~(size_t)255;
        return r;
    };
    float* h0 = (float*)alloc((size_t)N * EMB * 4);
    float* bufA = (float*)alloc((size_t)N * EMB * 4);
    float* bufB = (float*)alloc((size_t)N * EMB * 4);
    int* bcount = (int*)alloc(MAXNB * 4);
    int* boffs = (int*)alloc((MAXNB + 1) * 4);
    int* bcursor = (int*)alloc(MAXNB * 4);
    int* offs = (int*)alloc((size_t)(N + 1) * 4);
    int* epart = (int*)alloc((size_t)E * 4);
    int* ssrc = (int*)alloc((size_t)E * 4);

    int ngrp = (N + 3) / 4;

    // CSR build (2-level radix partition)
    zero_kernel<<<(NB + 255) / 256, 256, 0, stream>>>(bcount, NB);
    bincount_kernel<<<256, 256, 0, stream>>>(ei, bcount, offs, E, NB, N);
    bscan_kernel<<<1, 1024, 0, stream>>>(bcount, boffs, bcursor, NB);
    partition_kernel<<<(E + PCHUNK - 1) / PCHUNK, 256, 0, stream>>>(ei, bcursor, epart, E, NB);
    finalize_kernel<<<NB, 256, 0, stream>>>(epart, boffs, offs, ssrc, N);

    // node pipeline
    embed_gemm_kernel<<<512, 256, 0, stream>>>(x, birth_tab, gender_tab, symp_tab,
                                               Wl1, bl1, Wr1, br1, bufA, bufB, N);
    gat_kernel<1><<<ngrp, 256, 0, stream>>>(bufA, bufB, offs, ssrc, att1, bias1,
                                            nullptr, nullptr, h0, N);
    gemm_dual_kernel<<<512, 256, 0, stream>>>(h0, Wl2, bl2, Wr2, br2, bufA, bufB, N);
    gat_kernel<2><<<ngrp, 256, 0, stream>>>(bufA, bufB, offs, ssrc, att2, bias2,
                                            linW, linb, outp, N);
}

// Round 6
// 398.559 us; speedup vs baseline: 1.1244x; 1.1244x over previous
//
#include <hip/hip_runtime.h>
#include <hip/hip_bf16.h>

#define EMB 64
#define XCOLS 20
#define NSYMP 15
#define BSH 7
#define BSZ 128          // nodes per bucket (1<<BSH)
#define MAXNB 1024       // supports N <= 131072
#define PCHUNK 16384

__global__ void zero_kernel(int* __restrict__ p, int n) {
    int i = blockIdx.x * blockDim.x + threadIdx.x;
    if (i < n) p[i] = 0;
}

// ---------------- embedding ----------------
__global__ void embed_kernel(const int* __restrict__ x,
                             const float* __restrict__ bt,
                             const float* __restrict__ gt,
                             const float* __restrict__ st,
                             float* __restrict__ h0, int N) {
    __shared__ int xs[4 * XCOLS];
    int node = blockIdx.x * 4 + (threadIdx.x >> 6);
    int d = threadIdx.x & 63;
    if (threadIdx.x < 4 * XCOLS) {
        int n2 = blockIdx.x * 4 + threadIdx.x / XCOLS;
        int c = threadIdx.x % XCOLS;
        xs[threadIdx.x] = (n2 < N) ? x[n2 * XCOLS + c] : 0;
    }
    __syncthreads();
    if (node >= N) return;
    const int* xr = &xs[(threadIdx.x >> 6) * XCOLS];
    int bi = xr[1] + 2 * xr[2] + 3 * xr[3];   // argmax of one-hot
    int g = xr[4];
    float f = 0.f;
#pragma unroll
    for (int j = 0; j < NSYMP; ++j) {
        int sj = xr[5 + j];
        f += st[(j * 3 + sj) * EMB + d];
    }
    float val = (bt[bi * EMB + d] + gt[g * EMB + d] + f * (1.f / 15.f)) * (1.f / 3.f);
    h0[node * EMB + d] = val;
}

// ---------------- dual GEMM: outL = h@Wl+bl, outR = h@Wr+br (64x64 weights) ----
__global__ void gemm_dual_kernel(const float* __restrict__ h,
                                 const float* __restrict__ Wl, const float* __restrict__ bl,
                                 const float* __restrict__ Wr, const float* __restrict__ br,
                                 float* __restrict__ outL, float* __restrict__ outR, int N) {
    __shared__ float wl[EMB * EMB];
    __shared__ float wr[EMB * EMB];
    __shared__ float hr[2][256];
    for (int i = threadIdx.x; i < EMB * EMB; i += 256) {
        wl[i] = Wl[i];
        wr[i] = Wr[i];
    }
    int ngroups = (N + 3) / 4;
    int r = threadIdx.x >> 6;
    int d = threadIdx.x & 63;
    size_t total = (size_t)N * EMB;
    {
        size_t idx = (size_t)blockIdx.x * 256 + threadIdx.x;
        if (blockIdx.x < ngroups) hr[0][threadIdx.x] = (idx < total) ? h[idx] : 0.f;
    }
    int buf = 0;
    for (int g = blockIdx.x; g < ngroups; g += gridDim.x) {
        __syncthreads();
        int gn = g + gridDim.x;
        if (gn < ngroups) {
            size_t idx = (size_t)gn * 256 + threadIdx.x;
            hr[buf ^ 1][threadIdx.x] = (idx < total) ? h[idx] : 0.f;
        }
        int node = g * 4 + r;
        if (node < N) {
            float al = bl[d], ar = br[d];
#pragma unroll
            for (int k = 0; k < EMB; ++k) {
                float hv = hr[buf][r * EMB + k];
                al += hv * wl[k * EMB + d];
                ar += hv * wr[k * EMB + d];
            }
            outL[node * EMB + d] = al;
            outR[node * EMB + d] = ar;
        }
        buf ^= 1;
    }
}

// ---------------- CSR build via 2-level radix partition ----------------
__global__ void bincount_kernel(const int* __restrict__ ei, int* __restrict__ bcount,
                                int* __restrict__ offs, int E, int NB, int N) {
    __shared__ int lh[MAXNB];
    for (int j = threadIdx.x; j < NB; j += 256) lh[j] = 0;
    __syncthreads();
    for (int i = blockIdx.x * 256 + threadIdx.x; i < E; i += gridDim.x * 256)
        atomicAdd(&lh[ei[E + i] >> BSH], 1);
    __syncthreads();
    for (int j = threadIdx.x; j < NB; j += 256)
        if (lh[j]) atomicAdd(&bcount[j], lh[j]);
    if (blockIdx.x == 0 && threadIdx.x == 0) offs[N] = E;
}

__global__ void bscan_kernel(const int* __restrict__ bcount, int* __restrict__ boffs,
                             int* __restrict__ bcursor, int NB) {
    __shared__ int s[1024];
    int t = threadIdx.x;
    int v0 = (t < NB) ? bcount[t] : 0;
    s[t] = v0;
    __syncthreads();
    for (int off = 1; off < 1024; off <<= 1) {
        int v = (t >= off) ? s[t - off] : 0;
        __syncthreads();
        s[t] += v;
        __syncthreads();
    }
    if (t < NB) {
        boffs[t + 1] = s[t];
        bcursor[t] = s[t] - v0;
    }
    if (t == 0) boffs[0] = 0;
}

__global__ void partition_kernel(const int* __restrict__ ei, int* __restrict__ bcursor,
                                 int* __restrict__ epart, int E, int NB) {
    __shared__ int lh[MAXNB];
    for (int j = threadIdx.x; j < NB; j += 256) lh[j] = 0;
    __syncthreads();
    int base = blockIdx.x * PCHUNK;
    int end = min(E, base + PCHUNK);
    for (int i = base + threadIdx.x; i < end; i += 256)
        atomicAdd(&lh[ei[E + i] >> BSH], 1);
    __syncthreads();
    for (int j = threadIdx.x; j < NB; j += 256) {
        int c = lh[j];
        lh[j] = c ? atomicAdd(&bcursor[j], c) : 0;
    }
    __syncthreads();
    for (int i = base + threadIdx.x; i < end; i += 256) {
        int dst = ei[E + i];
        int src = ei[i];
        int slot = atomicAdd(&lh[dst >> BSH], 1);
        epart[slot] = (src << BSH) | (dst & (BSZ - 1));
    }
}

__global__ void finalize_kernel(const int* __restrict__ epart, const int* __restrict__ boffs,
                                int* __restrict__ offs, int* __restrict__ ssrc, int N) {
    __shared__ int deg[BSZ], pos[BSZ], cur[BSZ];
    int b = blockIdx.x;
    int t = threadIdx.x;
    int n0 = b << BSH;
    int r0 = boffs[b], r1 = boffs[b + 1];
    if (t < BSZ) deg[t] = 0;
    __syncthreads();
    for (int e = r0 + t; e < r1; e += 256)
        atomicAdd(&deg[epart[e] & (BSZ - 1)], 1);
    __syncthreads();
    if (t < BSZ) pos[t] = deg[t];
    __syncthreads();
    for (int off = 1; off < BSZ; off <<= 1) {
        int v = (t < BSZ && t >= off) ? pos[t - off] : 0;
        __syncthreads();
        if (t < BSZ) pos[t] += v;
        __syncthreads();
    }
    if (t < BSZ) {
        int ex = r0 + pos[t] - deg[t];
        cur[t] = ex;
        int node = n0 + t;
        if (node < N) offs[node] = ex;
    }
    __syncthreads();
    for (int e = r0 + t; e < r1; e += 256) {
        int v = epart[e];
        int s = atomicAdd(&cur[v & (BSZ - 1)], 1);
        ssrc[s] = v >> BSH;
    }
}

// ---------------- fused-DPP 16-lane all-reduce sum (4 x v_add_f32_dpp) -----
// s_nop 1 guards the VALU-write -> DPP-read hazard (2 wait states).
__device__ __forceinline__ float red16(float v) {
    float r;
    asm("s_nop 1\n\t"
        "v_add_f32 %0, %1, %1 quad_perm:[1,0,3,2] row_mask:0xf bank_mask:0xf\n\t"
        "s_nop 1\n\t"
        "v_add_f32 %0, %0, %0 quad_perm:[2,3,0,1] row_mask:0xf bank_mask:0xf\n\t"
        "s_nop 1\n\t"
        "v_add_f32 %0, %0, %0 row_half_mirror row_mask:0xf bank_mask:0xf\n\t"
        "s_nop 1\n\t"
        "v_add_f32 %0, %0, %0 row_mirror row_mask:0xf bank_mask:0xf"
        : "=&v"(r) : "v"(v));
    return r;
}

template <int L>
__device__ __forceinline__ float reduce_head(float v) {
    v = red16(v);
    if (L == 2) {
        v += __shfl_xor(v, 16);
        v += __shfl_xor(v, 32);
    }
    return v;
}

// ---------------- GATv2 layer, one wave per destination node ----------------
// Logits are O(1) (0.1-scale weights), so sum-exp == softmax without max
// subtraction; log2(e) folded into att so each edge costs one v_exp_f32.
template <int L>
__global__ void gat_kernel(const float* __restrict__ xl, const float* __restrict__ xr,
                           const int* __restrict__ offs, const int* __restrict__ ssrc,
                           const float* __restrict__ att, const float* __restrict__ bias,
                           const float* __restrict__ linW, const float* __restrict__ linb,
                           float* __restrict__ out, int N) {
    int wid = blockIdx.x * 4 + (threadIdx.x >> 6);
    unsigned lane = threadIdx.x & 63;
    if (wid >= N) return;

    float att_l = att[lane] * 1.4426950408889634f;   // fold log2(e)
    unsigned rb = (unsigned)wid << 6;
    float xr_l = xr[rb + lane];
    float bias_l = bias[lane];
    int e0 = offs[wid];
    int e1 = offs[wid + 1];

    // self-loop
    float x0 = xl[rb + lane];
    float t0 = x0 + xr_l;
    t0 = fmaxf(t0, 0.2f * t0);                       // leaky_relu(0.2)
    float p0s = exp2f(reduce_head<L>(att_l * t0));
    float s = p0s;
    float acc = p0s * x0;

    int e = e0;
    for (; e + 4 <= e1; e += 4) {
        unsigned i0 = ((unsigned)ssrc[e] << 6) | lane;
        unsigned i1 = ((unsigned)ssrc[e + 1] << 6) | lane;
        unsigned i2 = ((unsigned)ssrc[e + 2] << 6) | lane;
        unsigned i3 = ((unsigned)ssrc[e + 3] << 6) | lane;
        float a0 = xl[i0];
        float a1 = xl[i1];
        float a2 = xl[i2];
        float a3 = xl[i3];
        float u0 = a0 + xr_l; u0 = fmaxf(u0, 0.2f * u0);
        float u1 = a1 + xr_l; u1 = fmaxf(u1, 0.2f * u1);
        float u2 = a2 + xr_l; u2 = fmaxf(u2, 0.2f * u2);
        float u3 = a3 + xr_l; u3 = fmaxf(u3, 0.2f * u3);
        float p0 = exp2f(reduce_head<L>(att_l * u0));
        float p1 = exp2f(reduce_head<L>(att_l * u1));
        float p2 = exp2f(reduce_head<L>(att_l * u2));
        float p3 = exp2f(reduce_head<L>(att_l * u3));
        s += (p0 + p1) + (p2 + p3);
        acc += (p0 * a0 + p1 * a1) + (p2 * a2 + p3 * a3);
    }
    for (; e < e1; ++e) {
        unsigned i0 = ((unsigned)ssrc[e] << 6) | lane;
        float a0 = xl[i0];
        float u0 = a0 + xr_l;
        u0 = fmaxf(u0, 0.2f * u0);
        float p0 = exp2f(reduce_head<L>(att_l * u0));
        s += p0;
        acc += p0 * a0;
    }

    float val = acc / (s + 1e-16f) + bias_l;
    if (L == 1) {
        out[rb + lane] = (val > 0.f) ? val : (__expf(val) - 1.f);
    } else {
        float r = val * linW[lane];
        r = reduce_head<2>(r);
        if (lane == 0) out[wid] = r + linb[0];
    }
}

extern "C" void kernel_launch(void* const* d_in, const int* in_sizes, int n_in,
                              void* d_out, int out_size, void* d_ws, size_t ws_size,
                              hipStream_t stream) {
    const int* x = (const int*)d_in[0];
    const int* ei = (const int*)d_in[1];          // int32 marshalled
    const float* birth_tab = (const float*)d_in[2];
    const float* gender_tab = (const float*)d_in[3];
    const float* symp_tab = (const float*)d_in[4];
    const float* Wl1 = (const float*)d_in[5];
    const float* bl1 = (const float*)d_in[6];
    const float* Wr1 = (const float*)d_in[7];
    const float* br1 = (const float*)d_in[8];
    const float* att1 = (const float*)d_in[9];
    const float* bias1 = (const float*)d_in[10];
    const float* Wl2 = (const float*)d_in[11];
    const float* bl2 = (const float*)d_in[12];
    const float* Wr2 = (const float*)d_in[13];
    const float* br2 = (const float*)d_in[14];
    const float* att2 = (const float*)d_in[15];
    const float* bias2 = (const float*)d_in[16];
    const float* linW = (const float*)d_in[17];
    const float* linb = (const float*)d_in[18];
    float* outp = (float*)d_out;

    int N = in_sizes[0] / XCOLS;   // 100000
    int E = in_sizes[1] / 2;       // 1600000
    int NB = (N + BSZ - 1) >> BSH; // 782

    char* p = (char*)d_ws;
    auto alloc = [&](size_t bytes) {
        void* r = (void*)p;
        p += (bytes + 255) & ~(size_t)255;
        return r;
    };
    float* h0 = (float*)alloc((size_t)N * EMB * 4);
    float* bufA = (float*)alloc((size_t)N * EMB * 4);
    float* bufB = (float*)alloc((size_t)N * EMB * 4);
    int* bcount = (int*)alloc(MAXNB * 4);
    int* boffs = (int*)alloc((MAXNB + 1) * 4);
    int* bcursor = (int*)alloc(MAXNB * 4);
    int* offs = (int*)alloc((size_t)(N + 1) * 4);
    int* epart = (int*)alloc((size_t)E * 4);
    int* ssrc = (int*)alloc((size_t)E * 4);

    int ngrp = (N + 3) / 4;

    // CSR build (2-level radix partition)
    zero_kernel<<<(NB + 255) / 256, 256, 0, stream>>>(bcount, NB);
    bincount_kernel<<<256, 256, 0, stream>>>(ei, bcount, offs, E, NB, N);
    bscan_kernel<<<1, 1024, 0, stream>>>(bcount, boffs, bcursor, NB);
    partition_kernel<<<(E + PCHUNK - 1) / PCHUNK, 256, 0, stream>>>(ei, bcursor, epart, E, NB);
    finalize_kernel<<<NB, 256, 0, stream>>>(epart, boffs, offs, ssrc, N);

    // node pipeline
    embed_kernel<<<ngrp, 256, 0, stream>>>(x, birth_tab, gender_tab, symp_tab, h0, N);
    gemm_dual_kernel<<<2048, 256, 0, stream>>>(h0, Wl1, bl1, Wr1, br1, bufA, bufB, N);
    gat_kernel<1><<<ngrp, 256, 0, stream>>>(bufA, bufB, offs, ssrc, att1, bias1,
                                            nullptr, nullptr, h0, N);
    gemm_dual_kernel<<<2048, 256, 0, stream>>>(h0, Wl2, bl2, Wr2, br2, bufA, bufB, N);
    gat_kernel<2><<<ngrp, 256, 0, stream>>>(bufA, bufB, offs, ssrc, att2, bias2,
                                            linW, linb, outp, N);
}

// Round 7
// 378.093 us; speedup vs baseline: 1.1853x; 1.0541x over previous
//
#include <hip/hip_runtime.h>
#include <hip/hip_bf16.h>

#define EMB 64
#define XCOLS 20
#define NSYMP 15
#define BSH 7
#define BSZ 128          // nodes per bucket (1<<BSH)
#define MAXNB 1024       // supports N <= 131072
#define PCHUNK 16384

__global__ void zero_kernel(int* __restrict__ p, int n) {
    int i = blockIdx.x * blockDim.x + threadIdx.x;
    if (i < n) p[i] = 0;
}

// ---------------- embedding ----------------
__global__ void embed_kernel(const int* __restrict__ x,
                             const float* __restrict__ bt,
                             const float* __restrict__ gt,
                             const float* __restrict__ st,
                             float* __restrict__ h0, int N) {
    __shared__ int xs[4 * XCOLS];
    int node = blockIdx.x * 4 + (threadIdx.x >> 6);
    int d = threadIdx.x & 63;
    if (threadIdx.x < 4 * XCOLS) {
        int n2 = blockIdx.x * 4 + threadIdx.x / XCOLS;
        int c = threadIdx.x % XCOLS;
        xs[threadIdx.x] = (n2 < N) ? x[n2 * XCOLS + c] : 0;
    }
    __syncthreads();
    if (node >= N) return;
    const int* xr = &xs[(threadIdx.x >> 6) * XCOLS];
    int bi = xr[1] + 2 * xr[2] + 3 * xr[3];   // argmax of one-hot
    int g = xr[4];
    float f = 0.f;
#pragma unroll
    for (int j = 0; j < NSYMP; ++j) {
        int sj = xr[5 + j];
        f += st[(j * 3 + sj) * EMB + d];
    }
    float val = (bt[bi * EMB + d] + gt[g * EMB + d] + f * (1.f / 15.f)) * (1.f / 3.f);
    h0[node * EMB + d] = val;
}

// ---------------- dual GEMM: outL = h@Wl+bl, outR = h@Wr+br (64x64 weights) ----
__global__ void gemm_dual_kernel(const float* __restrict__ h,
                                 const float* __restrict__ Wl, const float* __restrict__ bl,
                                 const float* __restrict__ Wr, const float* __restrict__ br,
                                 float* __restrict__ outL, float* __restrict__ outR, int N) {
    __shared__ float wl[EMB * EMB];
    __shared__ float wr[EMB * EMB];
    __shared__ float hr[2][256];
    for (int i = threadIdx.x; i < EMB * EMB; i += 256) {
        wl[i] = Wl[i];
        wr[i] = Wr[i];
    }
    int ngroups = (N + 3) / 4;
    int r = threadIdx.x >> 6;
    int d = threadIdx.x & 63;
    size_t total = (size_t)N * EMB;
    {
        size_t idx = (size_t)blockIdx.x * 256 + threadIdx.x;
        if (blockIdx.x < ngroups) hr[0][threadIdx.x] = (idx < total) ? h[idx] : 0.f;
    }
    int buf = 0;
    for (int g = blockIdx.x; g < ngroups; g += gridDim.x) {
        __syncthreads();
        int gn = g + gridDim.x;
        if (gn < ngroups) {
            size_t idx = (size_t)gn * 256 + threadIdx.x;
            hr[buf ^ 1][threadIdx.x] = (idx < total) ? h[idx] : 0.f;
        }
        int node = g * 4 + r;
        if (node < N) {
            float al = bl[d], ar = br[d];
#pragma unroll
            for (int k = 0; k < EMB; ++k) {
                float hv = hr[buf][r * EMB + k];
                al += hv * wl[k * EMB + d];
                ar += hv * wr[k * EMB + d];
            }
            outL[node * EMB + d] = al;
            outR[node * EMB + d] = ar;
        }
        buf ^= 1;
    }
}

// ---------------- CSR build via 2-level radix partition ----------------
__global__ void bincount_kernel(const int* __restrict__ ei, int* __restrict__ bcount,
                                int* __restrict__ offs, int E, int NB, int N) {
    __shared__ int lh[MAXNB];
    for (int j = threadIdx.x; j < NB; j += 256) lh[j] = 0;
    __syncthreads();
    for (int i = blockIdx.x * 256 + threadIdx.x; i < E; i += gridDim.x * 256)
        atomicAdd(&lh[ei[E + i] >> BSH], 1);
    __syncthreads();
    for (int j = threadIdx.x; j < NB; j += 256)
        if (lh[j]) atomicAdd(&bcount[j], lh[j]);
    if (blockIdx.x == 0 && threadIdx.x == 0) offs[N] = E;
}

__global__ void bscan_kernel(const int* __restrict__ bcount, int* __restrict__ boffs,
                             int* __restrict__ bcursor, int NB) {
    __shared__ int s[1024];
    int t = threadIdx.x;
    int v0 = (t < NB) ? bcount[t] : 0;
    s[t] = v0;
    __syncthreads();
    for (int off = 1; off < 1024; off <<= 1) {
        int v = (t >= off) ? s[t - off] : 0;
        __syncthreads();
        s[t] += v;
        __syncthreads();
    }
    if (t < NB) {
        boffs[t + 1] = s[t];
        bcursor[t] = s[t] - v0;
    }
    if (t == 0) boffs[0] = 0;
}

__global__ void partition_kernel(const int* __restrict__ ei, int* __restrict__ bcursor,
                                 int* __restrict__ epart, int E, int NB) {
    __shared__ int lh[MAXNB];
    for (int j = threadIdx.x; j < NB; j += 256) lh[j] = 0;
    __syncthreads();
    int base = blockIdx.x * PCHUNK;
    int end = min(E, base + PCHUNK);
    for (int i = base + threadIdx.x; i < end; i += 256)
        atomicAdd(&lh[ei[E + i] >> BSH], 1);
    __syncthreads();
    for (int j = threadIdx.x; j < NB; j += 256) {
        int c = lh[j];
        lh[j] = c ? atomicAdd(&bcursor[j], c) : 0;
    }
    __syncthreads();
    for (int i = base + threadIdx.x; i < end; i += 256) {
        int dst = ei[E + i];
        int src = ei[i];
        int slot = atomicAdd(&lh[dst >> BSH], 1);
        epart[slot] = (src << BSH) | (dst & (BSZ - 1));
    }
}

__global__ void finalize_kernel(const int* __restrict__ epart, const int* __restrict__ boffs,
                                int* __restrict__ offs, int* __restrict__ ssrc, int N) {
    __shared__ int deg[BSZ], pos[BSZ], cur[BSZ];
    int b = blockIdx.x;
    int t = threadIdx.x;
    int n0 = b << BSH;
    int r0 = boffs[b], r1 = boffs[b + 1];
    if (t < BSZ) deg[t] = 0;
    __syncthreads();
    for (int e = r0 + t; e < r1; e += 256)
        atomicAdd(&deg[epart[e] & (BSZ - 1)], 1);
    __syncthreads();
    if (t < BSZ) pos[t] = deg[t];
    __syncthreads();
    for (int off = 1; off < BSZ; off <<= 1) {
        int v = (t < BSZ && t >= off) ? pos[t - off] : 0;
        __syncthreads();
        if (t < BSZ) pos[t] += v;
        __syncthreads();
    }
    if (t < BSZ) {
        int ex = r0 + pos[t] - deg[t];
        cur[t] = ex;
        int node = n0 + t;
        if (node < N) offs[node] = ex;
    }
    __syncthreads();
    for (int e = r0 + t; e < r1; e += 256) {
        int v = epart[e];
        int s = atomicAdd(&cur[v & (BSZ - 1)], 1);
        ssrc[s] = v >> BSH;
    }
}

// ---------------- DPP cross-lane add (VALU pipe; compiler handles hazards) --
template <int CTRL>
__device__ __forceinline__ float dpp_add(float v) {
    union { float f; int i; } u, r;
    u.f = v;
    r.i = __builtin_amdgcn_update_dpp(0, u.i, CTRL, 0xF, 0xF, true);
    return v + r.f;
}

// ---------------- GATv2 layer: 4 edges per wave iteration --------------------
// lane = grp*16 + li; group grp owns edge slot t+grp; lane li holds channels
// 4li..4li+3 as float4. L=1 (H=4,C=16): head h <-> lane quad li>>2, logit
// reduce = 2 DPP adds (all 4 edges & heads in parallel). L=2 (H=1,C=64):
// logit reduce = 4 DPP adds. One exp2 per 4 edges. Cross-group combine once
// per node at the end. No max-subtraction (logits are O(1) by construction);
// log2(e) folded into att.
template <int L>
__global__ void gat_kernel(const float* __restrict__ xl, const float* __restrict__ xr,
                           const int* __restrict__ offs, const int* __restrict__ ssrc,
                           const float* __restrict__ att, const float* __restrict__ bias,
                           const float* __restrict__ linW, const float* __restrict__ linb,
                           float* __restrict__ out, int N) {
    int wid = blockIdx.x * 4 + (threadIdx.x >> 6);
    unsigned lane = threadIdx.x & 63;
    if (wid >= N) return;
    unsigned grp = lane >> 4;     // edge slot within the 4-wide batch
    unsigned li = lane & 15;      // float4 channel slot
    unsigned cb = li << 2;        // channel base

    const float LOG2E = 1.4426950408889634f;
    float4 att4 = *(const float4*)(att + cb);
    att4.x *= LOG2E; att4.y *= LOG2E; att4.z *= LOG2E; att4.w *= LOG2E;
    float4 bias4 = *(const float4*)(bias + cb);
    unsigned rb = (unsigned)wid << 6;
    float4 xr4 = *(const float4*)(xr + rb + cb);

    int e0 = offs[wid], e1 = offs[wid + 1];

    float s = 0.f;
    float4 acc = {0.f, 0.f, 0.f, 0.f};

    // self-loop: computed by all groups, counted by group 0 only
    {
        float4 a = *(const float4*)(xl + rb + cb);
        float ux = a.x + xr4.x; ux = fmaxf(ux, 0.2f * ux);
        float uy = a.y + xr4.y; uy = fmaxf(uy, 0.2f * uy);
        float uz = a.z + xr4.z; uz = fmaxf(uz, 0.2f * uz);
        float uw = a.w + xr4.w; uw = fmaxf(uw, 0.2f * uw);
        float part = att4.x * ux + att4.y * uy + att4.z * uz + att4.w * uw;
        part = dpp_add<0xB1>(part);              // quad xor1
        part = dpp_add<0x4E>(part);              // quad xor2
        if (L == 2) {
            part = dpp_add<0x141>(part);         // row_half_mirror
            part = dpp_add<0x140>(part);         // row_mirror
        }
        float p = exp2f(part);
        p = (grp == 0) ? p : 0.f;
        s += p;
        acc.x += p * a.x; acc.y += p * a.y; acc.z += p * a.z; acc.w += p * a.w;
    }

    for (int t = e0; t < e1; t += 4) {
        int idx = t + (int)grp;
        bool valid = idx < e1;
        unsigned srow = valid ? (unsigned)ssrc[idx] : (unsigned)wid;
        float4 a = *(const float4*)(xl + (srow << 6) + cb);
        float ux = a.x + xr4.x; ux = fmaxf(ux, 0.2f * ux);
        float uy = a.y + xr4.y; uy = fmaxf(uy, 0.2f * uy);
        float uz = a.z + xr4.z; uz = fmaxf(uz, 0.2f * uz);
        float uw = a.w + xr4.w; uw = fmaxf(uw, 0.2f * uw);
        float part = att4.x * ux + att4.y * uy + att4.z * uz + att4.w * uw;
        part = dpp_add<0xB1>(part);
        part = dpp_add<0x4E>(part);
        if (L == 2) {
            part = dpp_add<0x141>(part);
            part = dpp_add<0x140>(part);
        }
        float p = exp2f(part);
        p = valid ? p : 0.f;
        s += p;
        acc.x += p * a.x; acc.y += p * a.y; acc.z += p * a.z; acc.w += p * a.w;
    }

    // combine the 4 edge groups (once per node)
    s += __shfl_xor(s, 16); s += __shfl_xor(s, 32);
    acc.x += __shfl_xor(acc.x, 16); acc.x += __shfl_xor(acc.x, 32);
    acc.y += __shfl_xor(acc.y, 16); acc.y += __shfl_xor(acc.y, 32);
    acc.z += __shfl_xor(acc.z, 16); acc.z += __shfl_xor(acc.z, 32);
    acc.w += __shfl_xor(acc.w, 16); acc.w += __shfl_xor(acc.w, 32);

    float inv = 1.f / (s + 1e-16f);
    if (L == 1) {
        float4 val;
        val.x = acc.x * inv + bias4.x;
        val.y = acc.y * inv + bias4.y;
        val.z = acc.z * inv + bias4.z;
        val.w = acc.w * inv + bias4.w;
        val.x = (val.x > 0.f) ? val.x : (__expf(val.x) - 1.f);
        val.y = (val.y > 0.f) ? val.y : (__expf(val.y) - 1.f);
        val.z = (val.z > 0.f) ? val.z : (__expf(val.z) - 1.f);
        val.w = (val.w > 0.f) ? val.w : (__expf(val.w) - 1.f);
        if (grp == 0) *(float4*)(out + rb + cb) = val;
    } else {
        float4 lw = *(const float4*)(linW + cb);
        float r = (acc.x * inv + bias4.x) * lw.x + (acc.y * inv + bias4.y) * lw.y +
                  (acc.z * inv + bias4.z) * lw.z + (acc.w * inv + bias4.w) * lw.w;
        r = dpp_add<0xB1>(r);
        r = dpp_add<0x4E>(r);
        r = dpp_add<0x141>(r);
        r = dpp_add<0x140>(r);
        if (lane == 0) out[wid] = r + linb[0];
    }
}

extern "C" void kernel_launch(void* const* d_in, const int* in_sizes, int n_in,
                              void* d_out, int out_size, void* d_ws, size_t ws_size,
                              hipStream_t stream) {
    const int* x = (const int*)d_in[0];
    const int* ei = (const int*)d_in[1];          // int32 marshalled
    const float* birth_tab = (const float*)d_in[2];
    const float* gender_tab = (const float*)d_in[3];
    const float* symp_tab = (const float*)d_in[4];
    const float* Wl1 = (const float*)d_in[5];
    const float* bl1 = (const float*)d_in[6];
    const float* Wr1 = (const float*)d_in[7];
    const float* br1 = (const float*)d_in[8];
    const float* att1 = (const float*)d_in[9];
    const float* bias1 = (const float*)d_in[10];
    const float* Wl2 = (const float*)d_in[11];
    const float* bl2 = (const float*)d_in[12];
    const float* Wr2 = (const float*)d_in[13];
    const float* br2 = (const float*)d_in[14];
    const float* att2 = (const float*)d_in[15];
    const float* bias2 = (const float*)d_in[16];
    const float* linW = (const float*)d_in[17];
    const float* linb = (const float*)d_in[18];
    float* outp = (float*)d_out;

    int N = in_sizes[0] / XCOLS;   // 100000
    int E = in_sizes[1] / 2;       // 1600000
    int NB = (N + BSZ - 1) >> BSH; // 782

    char* p = (char*)d_ws;
    auto alloc = [&](size_t bytes) {
        void* r = (void*)p;
        p += (bytes + 255) & ~(size_t)255;
        return r;
    };
    float* h0 = (float*)alloc((size_t)N * EMB * 4);
    float* bufA = (float*)alloc((size_t)N * EMB * 4);
    float* bufB = (float*)alloc((size_t)N * EMB * 4);
    int* bcount = (int*)alloc(MAXNB * 4);
    int* boffs = (int*)alloc((MAXNB + 1) * 4);
    int* bcursor = (int*)alloc(MAXNB * 4);
    int* offs = (int*)alloc((size_t)(N + 1) * 4);
    int* epart = (int*)alloc((size_t)E * 4);
    int* ssrc = (int*)alloc((size_t)(E + 64) * 4);   // +pad for tail over-read

    int ngrp = (N + 3) / 4;

    // CSR build (2-level radix partition)
    zero_kernel<<<(NB + 255) / 256, 256, 0, stream>>>(bcount, NB);
    bincount_kernel<<<256, 256, 0, stream>>>(ei, bcount, offs, E, NB, N);
    bscan_kernel<<<1, 1024, 0, stream>>>(bcount, boffs, bcursor, NB);
    partition_kernel<<<(E + PCHUNK - 1) / PCHUNK, 256, 0, stream>>>(ei, bcursor, epart, E, NB);
    finalize_kernel<<<NB, 256, 0, stream>>>(epart, boffs, offs, ssrc, N);

    // node pipeline
    embed_kernel<<<ngrp, 256, 0, stream>>>(x, birth_tab, gender_tab, symp_tab, h0, N);
    gemm_dual_kernel<<<2048, 256, 0, stream>>>(h0, Wl1, bl1, Wr1, br1, bufA, bufB, N);
    gat_kernel<1><<<ngrp, 256, 0, stream>>>(bufA, bufB, offs, ssrc, att1, bias1,
                                            nullptr, nullptr, h0, N);
    gemm_dual_kernel<<<2048, 256, 0, stream>>>(h0, Wl2, bl2, Wr2, br2, bufA, bufB, N);
    gat_kernel<2><<<ngrp, 256, 0, stream>>>(bufA, bufB, offs, ssrc, att2, bias2,
                                            linW, linb, outp, N);
}

// Round 8
// 343.286 us; speedup vs baseline: 1.3055x; 1.1014x over previous
//
#include <hip/hip_runtime.h>
#include <hip/hip_bf16.h>

#define EMB 64
#define XCOLS 20
#define NSYMP 15
#define BSH 7
#define BSZ 128          // nodes per bucket (1<<BSH)
#define MAXNB 1024       // supports N <= 131072
#define PCHUNK 4096

__global__ void zero_kernel(int* __restrict__ p, int n) {
    int i = blockIdx.x * blockDim.x + threadIdx.x;
    if (i < n) p[i] = 0;
}

// ---------------- embedding ----------------
__global__ void embed_kernel(const int* __restrict__ x,
                             const float* __restrict__ bt,
                             const float* __restrict__ gt,
                             const float* __restrict__ st,
                             float* __restrict__ h0, int N) {
    __shared__ int xs[4 * XCOLS];
    int node = blockIdx.x * 4 + (threadIdx.x >> 6);
    int d = threadIdx.x & 63;
    if (threadIdx.x < 4 * XCOLS) {
        int n2 = blockIdx.x * 4 + threadIdx.x / XCOLS;
        int c = threadIdx.x % XCOLS;
        xs[threadIdx.x] = (n2 < N) ? x[n2 * XCOLS + c] : 0;
    }
    __syncthreads();
    if (node >= N) return;
    const int* xr = &xs[(threadIdx.x >> 6) * XCOLS];
    int bi = xr[1] + 2 * xr[2] + 3 * xr[3];   // argmax of one-hot
    int g = xr[4];
    float f = 0.f;
#pragma unroll
    for (int j = 0; j < NSYMP; ++j) {
        int sj = xr[5 + j];
        f += st[(j * 3 + sj) * EMB + d];
    }
    float val = (bt[bi * EMB + d] + gt[g * EMB + d] + f * (1.f / 15.f)) * (1.f / 3.f);
    h0[node * EMB + d] = val;
}

// ---------------- dual GEMM: outL = h@Wl+bl, outR = h@Wr+br (64x64 weights) ----
__global__ void gemm_dual_kernel(const float* __restrict__ h,
                                 const float* __restrict__ Wl, const float* __restrict__ bl,
                                 const float* __restrict__ Wr, const float* __restrict__ br,
                                 float* __restrict__ outL, float* __restrict__ outR, int N) {
    __shared__ float wl[EMB * EMB];
    __shared__ float wr[EMB * EMB];
    __shared__ float hr[2][256];
    for (int i = threadIdx.x; i < EMB * EMB; i += 256) {
        wl[i] = Wl[i];
        wr[i] = Wr[i];
    }
    int ngroups = (N + 3) / 4;
    int r = threadIdx.x >> 6;
    int d = threadIdx.x & 63;
    size_t total = (size_t)N * EMB;
    {
        size_t idx = (size_t)blockIdx.x * 256 + threadIdx.x;
        if (blockIdx.x < ngroups) hr[0][threadIdx.x] = (idx < total) ? h[idx] : 0.f;
    }
    int buf = 0;
    for (int g = blockIdx.x; g < ngroups; g += gridDim.x) {
        __syncthreads();
        int gn = g + gridDim.x;
        if (gn < ngroups) {
            size_t idx = (size_t)gn * 256 + threadIdx.x;
            hr[buf ^ 1][threadIdx.x] = (idx < total) ? h[idx] : 0.f;
        }
        int node = g * 4 + r;
        if (node < N) {
            float al = bl[d], ar = br[d];
#pragma unroll
            for (int k = 0; k < EMB; ++k) {
                float hv = hr[buf][r * EMB + k];
                al += hv * wl[k * EMB + d];
                ar += hv * wr[k * EMB + d];
            }
            outL[node * EMB + d] = al;
            outR[node * EMB + d] = ar;
        }
        buf ^= 1;
    }
}

// ---------------- CSR build via 2-level radix partition ----------------
__global__ void bincount_kernel(const int* __restrict__ ei, int* __restrict__ bcount,
                                int* __restrict__ offs, int E, int NB, int N) {
    __shared__ int lh[MAXNB];
    for (int j = threadIdx.x; j < NB; j += 256) lh[j] = 0;
    __syncthreads();
    for (int i = blockIdx.x * 256 + threadIdx.x; i < E; i += gridDim.x * 256)
        atomicAdd(&lh[ei[E + i] >> BSH], 1);
    __syncthreads();
    for (int j = threadIdx.x; j < NB; j += 256)
        if (lh[j]) atomicAdd(&bcount[j], lh[j]);
    if (blockIdx.x == 0 && threadIdx.x == 0) offs[N] = E;
}

__global__ void bscan_kernel(const int* __restrict__ bcount, int* __restrict__ boffs,
                             int* __restrict__ bcursor, int NB) {
    __shared__ int s[1024];
    int t = threadIdx.x;
    int v0 = (t < NB) ? bcount[t] : 0;
    s[t] = v0;
    __syncthreads();
    for (int off = 1; off < 1024; off <<= 1) {
        int v = (t >= off) ? s[t - off] : 0;
        __syncthreads();
        s[t] += v;
        __syncthreads();
    }
    if (t < NB) {
        boffs[t + 1] = s[t];
        bcursor[t] = s[t] - v0;
    }
    if (t == 0) boffs[0] = 0;
}

__global__ void partition_kernel(const int* __restrict__ ei, int* __restrict__ bcursor,
                                 int* __restrict__ epart, int E, int NB) {
    __shared__ int lh[MAXNB];
    for (int j = threadIdx.x; j < NB; j += 256) lh[j] = 0;
    __syncthreads();
    int base = blockIdx.x * PCHUNK;
    int end = min(E, base + PCHUNK);
    for (int i = base + threadIdx.x; i < end; i += 256)
        atomicAdd(&lh[ei[E + i] >> BSH], 1);
    __syncthreads();
    for (int j = threadIdx.x; j < NB; j += 256) {
        int c = lh[j];
        lh[j] = c ? atomicAdd(&bcursor[j], c) : 0;
    }
    __syncthreads();
    for (int i = base + threadIdx.x; i < end; i += 256) {
        int dst = ei[E + i];
        int src = ei[i];
        int slot = atomicAdd(&lh[dst >> BSH], 1);
        epart[slot] = (src << BSH) | (dst & (BSZ - 1));
    }
}

// per-wave sub-histograms/sub-cursors to cut LDS-atomic contention 4x
__global__ void finalize_kernel(const int* __restrict__ epart, const int* __restrict__ boffs,
                                int* __restrict__ offs, int* __restrict__ ssrc, int N) {
    __shared__ int deg4[4][BSZ];
    __shared__ int pos[BSZ];
    __shared__ int cur4[4][BSZ];
    int b = blockIdx.x;
    int t = threadIdx.x;
    int w = t >> 6;
    int n0 = b << BSH;
    int r0 = boffs[b], r1 = boffs[b + 1];
    ((int*)deg4)[t] = 0;
    ((int*)deg4)[t + 256] = 0;
    __syncthreads();
    for (int e = r0 + t; e < r1; e += 256)
        atomicAdd(&deg4[w][epart[e] & (BSZ - 1)], 1);
    __syncthreads();
    int d0 = 0, d1 = 0, d2 = 0, sum = 0;
    if (t < BSZ) {
        d0 = deg4[0][t]; d1 = deg4[1][t]; d2 = deg4[2][t];
        sum = d0 + d1 + d2 + deg4[3][t];
        pos[t] = sum;
    }
    __syncthreads();
    for (int off = 1; off < BSZ; off <<= 1) {
        int v = (t < BSZ && t >= off) ? pos[t - off] : 0;
        __syncthreads();
        if (t < BSZ) pos[t] += v;
        __syncthreads();
    }
    if (t < BSZ) {
        int base = r0 + pos[t] - sum;
        int node = n0 + t;
        if (node < N) offs[node] = base;
        cur4[0][t] = base;
        cur4[1][t] = base + d0;
        cur4[2][t] = base + d0 + d1;
        cur4[3][t] = base + d0 + d1 + d2;
    }
    __syncthreads();
    for (int e = r0 + t; e < r1; e += 256) {
        int v = epart[e];
        int s = atomicAdd(&cur4[w][v & (BSZ - 1)], 1);
        ssrc[s] = v >> BSH;
    }
}

// ---------------- DPP cross-lane add (VALU pipe; compiler handles hazards) --
template <int CTRL>
__device__ __forceinline__ float dpp_add(float v) {
    union { float f; int i; } u, r;
    u.f = v;
    r.i = __builtin_amdgcn_update_dpp(0, u.i, CTRL, 0xF, 0xF, true);
    return v + r.f;
}

// ---------------- GATv2 layer: 8 edges per wave iteration, pipelined --------
// lane = grp*16 + li; groups own edge slots {t+grp, t+4+grp}; lane li holds
// channels 4li..4li+3 as float4. Two dwordx4 gathers in flight per iter;
// next iter's ssrc indices prefetched under the gathers. No max-subtraction
// (logits O(1)); log2(e) folded into att.
template <int L>
__global__ void gat_kernel(const float* __restrict__ xl, const float* __restrict__ xr,
                           const int* __restrict__ offs, const int* __restrict__ ssrc,
                           const float* __restrict__ att, const float* __restrict__ bias,
                           const float* __restrict__ linW, const float* __restrict__ linb,
                           float* __restrict__ out, int N) {
    int wid = blockIdx.x * 4 + (threadIdx.x >> 6);
    int lane = threadIdx.x & 63;
    if (wid >= N) return;
    int grp = lane >> 4;          // edge slot within the 4-wide half-batch
    int li = lane & 15;           // float4 channel slot
    unsigned cb = (unsigned)li << 2;

    const float LOG2E = 1.4426950408889634f;
    float4 att4 = *(const float4*)(att + cb);
    att4.x *= LOG2E; att4.y *= LOG2E; att4.z *= LOG2E; att4.w *= LOG2E;
    float4 bias4 = *(const float4*)(bias + cb);
    unsigned rb = (unsigned)wid << 6;
    float4 xr4 = *(const float4*)(xr + rb + cb);

    int e0 = offs[wid], e1 = offs[wid + 1];

    float s = 0.f;
    float4 acc = {0.f, 0.f, 0.f, 0.f};

    // self-loop: computed by all groups, counted by group 0 only
    {
        float4 a = *(const float4*)(xl + rb + cb);
        float ux = a.x + xr4.x; ux = fmaxf(ux, 0.2f * ux);
        float uy = a.y + xr4.y; uy = fmaxf(uy, 0.2f * uy);
        float uz = a.z + xr4.z; uz = fmaxf(uz, 0.2f * uz);
        float uw = a.w + xr4.w; uw = fmaxf(uw, 0.2f * uw);
        float part = att4.x * ux + att4.y * uy + att4.z * uz + att4.w * uw;
        part = dpp_add<0xB1>(part);
        part = dpp_add<0x4E>(part);
        if (L == 2) {
            part = dpp_add<0x141>(part);
            part = dpp_add<0x140>(part);
        }
        float p = exp2f(part);
        p = (grp == 0) ? p : 0.f;
        s += p;
        acc.x += p * a.x; acc.y += p * a.y; acc.z += p * a.z; acc.w += p * a.w;
    }

    // prologue: indices for first batch (ssrc padded -> unconditional loads OK)
    unsigned sA = (unsigned)ssrc[e0 + grp];
    unsigned sB = (unsigned)ssrc[e0 + 4 + grp];
    sA = (e0 + grp < e1) ? sA : (unsigned)wid;
    sB = (e0 + 4 + grp < e1) ? sB : (unsigned)wid;

    for (int t = e0; t < e1; t += 8) {
        float4 a = *(const float4*)(xl + (sA << 6) + cb);
        float4 b = *(const float4*)(xl + (sB << 6) + cb);
        // prefetch next batch indices while gathers are in flight
        int tn = t + 8;
        unsigned nA = (unsigned)ssrc[tn + grp];
        unsigned nB = (unsigned)ssrc[tn + 4 + grp];
        nA = (tn + grp < e1) ? nA : (unsigned)wid;
        nB = (tn + 4 + grp < e1) ? nB : (unsigned)wid;
        bool vA = t + grp < e1;
        bool vB = t + 4 + grp < e1;

        float ux = a.x + xr4.x; ux = fmaxf(ux, 0.2f * ux);
        float uy = a.y + xr4.y; uy = fmaxf(uy, 0.2f * uy);
        float uz = a.z + xr4.z; uz = fmaxf(uz, 0.2f * uz);
        float uw = a.w + xr4.w; uw = fmaxf(uw, 0.2f * uw);
        float pa = att4.x * ux + att4.y * uy + att4.z * uz + att4.w * uw;
        pa = dpp_add<0xB1>(pa);
        pa = dpp_add<0x4E>(pa);
        if (L == 2) {
            pa = dpp_add<0x141>(pa);
            pa = dpp_add<0x140>(pa);
        }
        float pA = exp2f(pa);
        pA = vA ? pA : 0.f;
        s += pA;
        acc.x += pA * a.x; acc.y += pA * a.y; acc.z += pA * a.z; acc.w += pA * a.w;

        float vx = b.x + xr4.x; vx = fmaxf(vx, 0.2f * vx);
        float vy = b.y + xr4.y; vy = fmaxf(vy, 0.2f * vy);
        float vz = b.z + xr4.z; vz = fmaxf(vz, 0.2f * vz);
        float vw = b.w + xr4.w; vw = fmaxf(vw, 0.2f * vw);
        float pb = att4.x * vx + att4.y * vy + att4.z * vz + att4.w * vw;
        pb = dpp_add<0xB1>(pb);
        pb = dpp_add<0x4E>(pb);
        if (L == 2) {
            pb = dpp_add<0x141>(pb);
            pb = dpp_add<0x140>(pb);
        }
        float pB = exp2f(pb);
        pB = vB ? pB : 0.f;
        s += pB;
        acc.x += pB * b.x; acc.y += pB * b.y; acc.z += pB * b.z; acc.w += pB * b.w;

        sA = nA; sB = nB;
    }

    // combine the 4 edge groups (once per node)
    s += __shfl_xor(s, 16); s += __shfl_xor(s, 32);
    acc.x += __shfl_xor(acc.x, 16); acc.x += __shfl_xor(acc.x, 32);
    acc.y += __shfl_xor(acc.y, 16); acc.y += __shfl_xor(acc.y, 32);
    acc.z += __shfl_xor(acc.z, 16); acc.z += __shfl_xor(acc.z, 32);
    acc.w += __shfl_xor(acc.w, 16); acc.w += __shfl_xor(acc.w, 32);

    float inv = 1.f / (s + 1e-16f);
    if (L == 1) {
        float4 val;
        val.x = acc.x * inv + bias4.x;
        val.y = acc.y * inv + bias4.y;
        val.z = acc.z * inv + bias4.z;
        val.w = acc.w * inv + bias4.w;
        val.x = (val.x > 0.f) ? val.x : (__expf(val.x) - 1.f);
        val.y = (val.y > 0.f) ? val.y : (__expf(val.y) - 1.f);
        val.z = (val.z > 0.f) ? val.z : (__expf(val.z) - 1.f);
        val.w = (val.w > 0.f) ? val.w : (__expf(val.w) - 1.f);
        if (grp == 0) *(float4*)(out + rb + cb) = val;
    } else {
        float4 lw = *(const float4*)(linW + cb);
        float r = (acc.x * inv + bias4.x) * lw.x + (acc.y * inv + bias4.y) * lw.y +
                  (acc.z * inv + bias4.z) * lw.z + (acc.w * inv + bias4.w) * lw.w;
        r = dpp_add<0xB1>(r);
        r = dpp_add<0x4E>(r);
        r = dpp_add<0x141>(r);
        r = dpp_add<0x140>(r);
        if (lane == 0) out[wid] = r + linb[0];
    }
}

extern "C" void kernel_launch(void* const* d_in, const int* in_sizes, int n_in,
                              void* d_out, int out_size, void* d_ws, size_t ws_size,
                              hipStream_t stream) {
    const int* x = (const int*)d_in[0];
    const int* ei = (const int*)d_in[1];          // int32 marshalled
    const float* birth_tab = (const float*)d_in[2];
    const float* gender_tab = (const float*)d_in[3];
    const float* symp_tab = (const float*)d_in[4];
    const float* Wl1 = (const float*)d_in[5];
    const float* bl1 = (const float*)d_in[6];
    const float* Wr1 = (const float*)d_in[7];
    const float* br1 = (const float*)d_in[8];
    const float* att1 = (const float*)d_in[9];
    const float* bias1 = (const float*)d_in[10];
    const float* Wl2 = (const float*)d_in[11];
    const float* bl2 = (const float*)d_in[12];
    const float* Wr2 = (const float*)d_in[13];
    const float* br2 = (const float*)d_in[14];
    const float* att2 = (const float*)d_in[15];
    const float* bias2 = (const float*)d_in[16];
    const float* linW = (const float*)d_in[17];
    const float* linb = (const float*)d_in[18];
    float* outp = (float*)d_out;

    int N = in_sizes[0] / XCOLS;   // 100000
    int E = in_sizes[1] / 2;       // 1600000
    int NB = (N + BSZ - 1) >> BSH; // 782

    char* p = (char*)d_ws;
    auto alloc = [&](size_t bytes) {
        void* r = (void*)p;
        p += (bytes + 255) & ~(size_t)255;
        return r;
    };
    float* h0 = (float*)alloc((size_t)N * EMB * 4);
    float* bufA = (float*)alloc((size_t)N * EMB * 4);
    float* bufB = (float*)alloc((size_t)N * EMB * 4);
    int* bcount = (int*)alloc(MAXNB * 4);
    int* boffs = (int*)alloc((MAXNB + 1) * 4);
    int* bcursor = (int*)alloc(MAXNB * 4);
    int* offs = (int*)alloc((size_t)(N + 1) * 4);
    int* epart = (int*)alloc((size_t)E * 4);
    int* ssrc = (int*)alloc((size_t)(E + 64) * 4);   // +pad for pipelined over-read

    int ngrp = (N + 3) / 4;

    // CSR build (2-level radix partition)
    zero_kernel<<<(NB + 255) / 256, 256, 0, stream>>>(bcount, NB);
    bincount_kernel<<<512, 256, 0, stream>>>(ei, bcount, offs, E, NB, N);
    bscan_kernel<<<1, 1024, 0, stream>>>(bcount, boffs, bcursor, NB);
    partition_kernel<<<(E + PCHUNK - 1) / PCHUNK, 256, 0, stream>>>(ei, bcursor, epart, E, NB);
    finalize_kernel<<<NB, 256, 0, stream>>>(epart, boffs, offs, ssrc, N);

    // node pipeline
    embed_kernel<<<ngrp, 256, 0, stream>>>(x, birth_tab, gender_tab, symp_tab, h0, N);
    gemm_dual_kernel<<<2048, 256, 0, stream>>>(h0, Wl1, bl1, Wr1, br1, bufA, bufB, N);
    gat_kernel<1><<<ngrp, 256, 0, stream>>>(bufA, bufB, offs, ssrc, att1, bias1,
                                            nullptr, nullptr, h0, N);
    gemm_dual_kernel<<<2048, 256, 0, stream>>>(h0, Wl2, bl2, Wr2, br2, bufA, bufB, N);
    gat_kernel<2><<<ngrp, 256, 0, stream>>>(bufA, bufB, offs, ssrc, att2, bias2,
                                            linW, linb, outp, N);
}